// Round 7
// baseline (672.466 us; speedup 1.0000x reference)
//
#include <hip/hip_runtime.h>
#include <math.h>

// Problem constants (reference: B,N,M,C = 4,4096,4096,256)
#define BB 4
#define BN 4096          // N == M == 4096
#define CC 256
constexpr float T2      = 0.04f;                     // DIST_THRESH^2
constexpr float INV_EPS = (float)(1.0 / 0.01000001); // 1/(EPSILON + 1e-8)

__device__ __forceinline__ int cell_of(float x, float y) {
  int cx = (int)(x * 5.0f); cx = cx < 0 ? 0 : (cx > 4 ? 4 : cx);
  int cy = (int)(y * 5.0f); cy = cy < 0 ? 0 : (cy > 4 ? 4 : cy);
  return cy * 5 + cx;
}

// async 16B/lane global->LDS DMA: LDS dest = wave-uniform base + lane*16.
__device__ __forceinline__ void dma16(const void* g, void* l) {
  __builtin_amdgcn_global_load_lds(
      (const __attribute__((address_space(1))) void*)g,
      (__attribute__((address_space(3))) void*)l, 16, 0, 0);
}

// ------------------------------------------------- fused binning (8 blk) ----
// Per-(side,batch) block: count its own 4096 points into LDS, scan 25 cells,
// scatter perm + cell-sorted packs. Block 0 also zeroes the Zc leak counters.
__global__ __launch_bounds__(256) void k_bin(
    const float* __restrict__ tlocs, const float* __restrict__ slocs,
    const int* __restrict__ tmask, const int* __restrict__ smask,
    int* __restrict__ Zc,
    int* __restrict__ starts_t, int* __restrict__ starts_s,
    int* __restrict__ perm_t, int* __restrict__ perm_s,
    float4* __restrict__ t_sorted, float4* __restrict__ s_sorted) {
  const int which = blockIdx.x & 1, b = blockIdx.x >> 1;   // grid = 2*B
  const float* locs = which ? slocs : tlocs;
  const int*   mask = which ? smask : tmask;
  int* starts       = which ? starts_s : starts_t;
  int* perm         = which ? perm_s : perm_t;
  float4* pack      = which ? s_sorted : t_sorted;
  const int tid = threadIdx.x;
  if (blockIdx.x == 0) Zc[tid] = 0;                        // 256 ints = 1 KB
  __shared__ int cnt[25];
  __shared__ int st[26];
  __shared__ int cur[25];
  if (tid < 25) cnt[tid] = 0;
  __syncthreads();
  for (int i = tid; i < BN; i += 256)
    atomicAdd(&cnt[cell_of(locs[(b * BN + i) * 2], locs[(b * BN + i) * 2 + 1])], 1);
  __syncthreads();
  if (tid == 0) {
    int acc = 0;
    for (int c = 0; c < 25; c++) { st[c] = acc; acc += cnt[c]; }
    st[25] = acc;                                          // == 4096
  }
  __syncthreads();
  if (tid < 25) cur[tid] = st[tid];
  if (tid < 26) starts[b * 32 + tid] = st[tid];
  __syncthreads();
  for (int i = tid; i < BN; i += 256) {
    float x = locs[(b * BN + i) * 2], y = locs[(b * BN + i) * 2 + 1];
    int pos = atomicAdd(&cur[cell_of(x, y)], 1);
    perm[b * BN + pos] = i;
    pack[b * BN + pos] = make_float4(x, y, 0.f, mask[b * BN + i] ? 1.f : 0.f);
  }
}

// ------------------------------------------------------ sparse Sinkhorn -----
// r4-verified. 4 rows per wave, plain-sum (no online max): finite terms
// t = logK + opp.z are bounded (|z| <~ 65 worst case) -> sum(exp) can't
// overflow f32; masked terms t=-3e30 -> __expf == exactly 0. Leak terms
// (exp(0)=1 each) folded via per-batch Z count; empty rows -> exactly 1e9f
// (same as dense: -1e9 + log(count) rounds back to -1e9). Union-box over-scan
// is masked by d2 < T2. zero_invalid mirrors v = where(source_valid, v, 0).
__global__ __launch_bounds__(256) void k_sink(const float4* __restrict__ opp,
                                              float4* __restrict__ own,
                                              const int* __restrict__ opp_starts,
                                              const int* __restrict__ Zin,
                                              int* __restrict__ Zout,
                                              int zero_invalid) {
  const int wv   = threadIdx.x >> 6;            // wave 0..3
  const int lane = threadIdx.x & 63;
  const int rowb = blockIdx.x * 16 + wv * 4;    // 4 rows/wave; 1024 blocks exact
  const int b    = rowb >> 12;                  // batch (no group crosses batch)
  float4 me[4];
  float  s[4] = {0.f, 0.f, 0.f, 0.f};
  int ryLo = 5, ryHi = -1, rxLo = 5, rxHi = -1;
  #pragma unroll
  for (int i = 0; i < 4; i++) {
    me[i] = own[rowb + i];
    if (me[i].w != 0.f) {                        // invalid rows: no finite terms
      int cell = cell_of(me[i].x, me[i].y);
      int cy = cell / 5, cx = cell % 5;
      ryLo = min(ryLo, max(cy - 1, 0)); ryHi = max(ryHi, min(cy + 1, 4));
      rxLo = min(rxLo, max(cx - 1, 0)); rxHi = max(rxHi, min(cx + 1, 4));
    }
  }
  for (int ry = ryLo; ry <= ryHi; ry++) {
    const int r0 = opp_starts[b * 32 + ry * 5 + rxLo];
    const int r1 = opp_starts[b * 32 + ry * 5 + rxHi + 1];  // contiguous cells
    for (int j = r0 + lane; j < r1; j += 64) {
      float4 o = opp[b * BN + j];
      #pragma unroll
      for (int i = 0; i < 4; i++) {
        float dx = me[i].x - o.x, dy = me[i].y - o.y;
        float d2 = fmaf(dx, dx, dy * dy);
        bool  c  = (d2 < T2) && (o.w != 0.f) && (me[i].w != 0.f);
        float t  = c ? fmaf(d2, -INV_EPS, o.z) : -3e30f;    // masked: exp -> 0
        s[i] += __expf(t);
      }
    }
  }
  #pragma unroll
  for (int i = 0; i < 4; i++)
    for (int off = 32; off > 0; off >>= 1) s[i] += __shfl_xor(s[i], off);
  if (lane == 0) {
    const float Zf = (float)Zin[b];
    #pragma unroll
    for (int i = 0; i < 4; i++) {
      float ss  = s[i] + Zf;                     // leak terms: exp(0)=1, Z of them
      float val = (ss > 0.f) ? -logf(ss) : 1.0e9f;  // empty row -> exactly 1e9f
      if (zero_invalid && me[i].w == 0.f) val = 0.f;
      own[rowb + i] = make_float4(me[i].x, me[i].y, val, me[i].w);
      if (val == 1.0e9f) atomicAdd(&Zout[b], 1);
    }
  }
}

// ------------------------------------------------- sparse attn @ feats ------
// r6 DMA double-buffered structure + 6-way source split (was 3-way).
// blockIdx.y = cell*6 + sub; sub>>1 selects the box cell-row, sub&1 selects
// the CH-aligned HALF of that row's source range. Total scanned sources are
// PARTITIONED (not duplicated) -> FETCH unchanged; per-output atomic
// accumulations rise 3 -> up to 6 (out zeroed first). Rationale: occupancy
// was tail-quantized (1650 blocks, LDS caps 4/CU -> 1.6 fill cohorts, 22%
// occupancy); 2x blocks halve serial length and smooth the tail.
// Per 16-source round (ONE raw barrier):
//   [vmcnt(0); s_barrier; sched_barrier] -> DMA(k) landed, buf[k-1] free.
//   issue DMA(k+1), prefetch s_rows(k+1)/perm idx(k+2) to regs,
//   wave-local attn(k) (cols w*8..+7, same-wave lgkmcnt ordering),
//   MAC(k) from fL[buf]. DMA latency hides under the ~1024-cyc MAC.
#define MAXCH 12   // 12*32 = 384 targets/cell upper bound
#define CH 16      // sources per round

__global__ __launch_bounds__(256) void k_out(
    const float* __restrict__ feats, const float4* __restrict__ t_sorted,
    const float4* __restrict__ s_sorted, const int* __restrict__ perm_t,
    const int* __restrict__ perm_s, const int* __restrict__ starts_t,
    const int* __restrict__ starts_s, float* __restrict__ out) {
  const int b = blockIdx.z;
  const int cell = blockIdx.y / 6, sub = blockIdx.y % 6;
  const int cy = cell / 5, cx = cell % 5;
  const int ry = cy + (sub >> 1) - 1;
  if (ry < 0 || ry > 4) return;                            // uniform early-exit
  const int t0 = starts_t[b * 32 + cell], t1 = starts_t[b * 32 + cell + 1];
  const int base = t0 + blockIdx.x * 32;
  if (base >= t1) return;
  const int rx0 = max(cx - 1, 0), rx1 = min(cx + 1, 4);
  const int sA = starts_s[b * 32 + ry * 5 + rx0];
  const int sE = starts_s[b * 32 + ry * 5 + rx1 + 1];
  if (sA >= sE) return;
  // CH-aligned half-split of [sA, sE)
  const int rounds = (sE - sA + CH - 1) / CH;
  const int rA = (rounds + 1) >> 1;
  int s0, s1;
  if ((sub & 1) == 0) { s0 = sA; s1 = min(sA + rA * CH, sE); }
  else                { s0 = sA + rA * CH; s1 = sE; if (s0 >= s1) return; }
  const int nt = min(32, t1 - base);

  __shared__ float4 tL[32];                    // x, y, u, tv
  __shared__ int    morg[32];
  __shared__ __align__(16) float attnL[16 * 36];   // stride 36: bank-spread
  __shared__ __align__(16) float fL[2 * CH * 256]; // 32 KB double-buffered feats

  const int tid  = threadIdx.x;
  const int lane = tid & 63;
  const int w    = tid >> 6;                   // wave 0..3

  if (tid < 32) {
    if (tid < nt) {
      tL[tid]   = t_sorted[b * BN + base + tid];
      morg[tid] = perm_t[b * BN + base + tid];
    } else {
      tL[tid]   = make_float4(0.f, 0.f, 0.f, 0.f);         // tv=0 -> attn 0
      morg[tid] = 0;
    }
  }
  __syncthreads();

  const int tmg  = tid >> 5;                   // consumer: targets tmg*4..+3
  const int chg  = tid & 31;                   // consumer: channels chg*4..+3,+128
  const int tmp_ = w * 8 + (lane & 7);         // producer: attn column (wave-local)
  const int nnA  = lane >> 3, nnB = nnA + 8;   // producer: attn rows
  const float4 t4p = tL[tmp_];                 // hoisted target row (regs)
  const int sB = b * BN;

  // ---- prologue: round-0 prefetches + DMA(0) into buf 0 --------------------
  float4 psA = s_sorted[sB + min(s0 + nnA, s1 - 1)];
  float4 psB = s_sorted[sB + min(s0 + nnB, s1 - 1)];
  float4 pnA, pnB;
  int sidxN[4];
  {
    int s0i[4];
    #pragma unroll
    for (int q = 0; q < 4; q++)
      s0i[q] = perm_s[sB + min(s0 + q * 4 + w, s1 - 1)];
    #pragma unroll
    for (int q = 0; q < 4; q++)
      dma16((const char*)feats + ((size_t)((b << 12) + s0i[q]) << 10) + (size_t)lane * 16,
            (void*)&fL[(q * 4 + w) * 256]);
    #pragma unroll
    for (int q = 0; q < 4; q++)                // indices for round 1's DMA
      sidxN[q] = perm_s[sB + min(s0 + CH + q * 4 + w, s1 - 1)];
  }

  float acc[4][8];
  #pragma unroll
  for (int i = 0; i < 4; i++)
    #pragma unroll
    for (int j = 0; j < 8; j++) acc[i][j] = 0.f;

  int bb = 0;
  for (int n0 = s0; n0 < s1; n0 += CH, bb ^= 1) {
    asm volatile("s_waitcnt vmcnt(0)" ::: "memory");       // own DMA+prefetch done
    __builtin_amdgcn_s_barrier();                          // publish to all waves
    __builtin_amdgcn_sched_barrier(0);
    const int n1 = n0 + CH;
    const bool more = (n1 < s1);                           // uniform
    if (more) {                                            // issue next round
      #pragma unroll
      for (int q = 0; q < 4; q++)
        dma16((const char*)feats + ((size_t)((b << 12) + sidxN[q]) << 10) + (size_t)lane * 16,
              (void*)&fL[((bb ^ 1) * CH + q * 4 + w) * 256]);
      pnA = s_sorted[sB + min(n1 + nnA, s1 - 1)];
      pnB = s_sorted[sB + min(n1 + nnB, s1 - 1)];
      #pragma unroll
      for (int q = 0; q < 4; q++)
        sidxN[q] = perm_s[sB + min(n1 + CH + q * 4 + w, s1 - 1)];
    }
    {                                          // attn(k): 2 wave-local entries
      float dx = t4p.x - psA.x, dy = t4p.y - psA.y;
      float d2 = fmaf(dx, dx, dy * dy);
      bool  c  = (n0 + nnA < s1) && (d2 < T2) && (psA.w != 0.f) && (t4p.w != 0.f);
      attnL[nnA * 36 + tmp_] = c ? __expf(fmaf(d2, -INV_EPS, t4p.z + psA.z)) : 0.f;
      dx = t4p.x - psB.x; dy = t4p.y - psB.y;
      d2 = fmaf(dx, dx, dy * dy);
      c  = (n0 + nnB < s1) && (d2 < T2) && (psB.w != 0.f) && (t4p.w != 0.f);
      attnL[nnB * 36 + tmp_] = c ? __expf(fmaf(d2, -INV_EPS, t4p.z + psB.z)) : 0.f;
    }
    const float* fb = &fL[bb * CH * 256];
    #pragma unroll 4                           // MAC: 3 ds_read_b128 per 32 FMA
    for (int nn = 0; nn < 16; nn++) {
      const float4 av = *(const float4*)&attnL[nn * 36 + tmg * 4];
      const float4 f0 = *(const float4*)&fb[nn * 256 + chg * 4];
      const float4 f1 = *(const float4*)&fb[nn * 256 + 128 + chg * 4];
      float avv[4] = {av.x, av.y, av.z, av.w};
      float ff[8]  = {f0.x, f0.y, f0.z, f0.w, f1.x, f1.y, f1.z, f1.w};
      #pragma unroll
      for (int i = 0; i < 4; i++)
        #pragma unroll
        for (int j = 0; j < 8; j++)
          acc[i][j] = fmaf(avv[i], ff[j], acc[i][j]);
    }
    if (more) { psA = pnA; psB = pnB; }        // rotate s-row prefetch
  }
  #pragma unroll
  for (int i = 0; i < 4; i++) {
    int tm = tmg * 4 + i;
    if (tm < nt) {
      float* op = out + (((b << 12) + morg[tm]) << 8) + chg * 4;
      #pragma unroll
      for (int j = 0; j < 4; j++) atomicAdd(op + j,       acc[i][j]);
      #pragma unroll
      for (int j = 0; j < 4; j++) atomicAdd(op + 128 + j, acc[i][j + 4]);
    }
  }
}

// ----------------------------------------------------------------- launch ---
extern "C" void kernel_launch(void* const* d_in, const int* in_sizes, int n_in,
                              void* d_out, int out_size, void* d_ws, size_t ws_size,
                              hipStream_t stream) {
  const float* feats = (const float*)d_in[0];   // [B,N,C] f32
  const float* slocs = (const float*)d_in[1];   // [B,N,2] f32
  const float* tlocs = (const float*)d_in[2];   // [B,M,2] f32
  const int*   smask = (const int*)d_in[3];     // [B,N] int32 (bool)
  const int*   tmask = (const int*)d_in[4];     // [B,M] int32 (bool)
  float* out = (float*)d_out;

  char* ws = (char*)d_ws;                       // ~660 KB used
  int*    Zc       = (int*)(ws + 1024);         //   256 ints; slot 0 stays 0
  int*    starts_t = (int*)(ws + 2048);         //   512 B
  int*    starts_s = (int*)(ws + 2560);         //   512 B
  int*    perm_t   = (int*)(ws + 4096);         //   64 KB
  int*    perm_s   = (int*)(ws + 69632);        //   64 KB
  float4* s_sorted = (float4*)(ws + 135168);    //  256 KB (x,y,v,sv) cell-sorted
  float4* t_sorted = (float4*)(ws + 397312);    //  256 KB (x,y,u,tv) cell-sorted

  hipMemsetAsync(out, 0, (size_t)out_size * sizeof(float), stream);
  k_bin<<<8, 256, 0, stream>>>(tlocs, slocs, tmask, smask, Zc,
                               starts_t, starts_s, perm_t, perm_s,
                               t_sorted, s_sorted);
  for (int it = 0; it < 3; it++) {
    // u-update: Zin = leak count of current v (slot 0 = zeros for it==0)
    k_sink<<<1024, 256, 0, stream>>>(s_sorted, t_sorted, starts_s,
                                     Zc + (it == 0 ? 0 : (2 * it) * 4),
                                     Zc + (2 * it + 1) * 4, 0);
    // v-update: Zin = leak count of u just written
    k_sink<<<1024, 256, 0, stream>>>(t_sorted, s_sorted, starts_t,
                                     Zc + (2 * it + 1) * 4,
                                     Zc + (2 * it + 2) * 4, 1);
  }
  k_out<<<dim3(MAXCH, 150, BB), 256, 0, stream>>>(feats, t_sorted, s_sorted,
                                                  perm_t, perm_s, starts_t,
                                                  starts_s, out);
}

// Round 8
// 557.631 us; speedup vs baseline: 1.2059x; 1.2059x over previous
//
#include <hip/hip_runtime.h>
#include <math.h>

// Problem constants (reference: B,N,M,C = 4,4096,4096,256)
#define BB 4
#define BN 4096          // N == M == 4096
#define CC 256
constexpr float T2      = 0.04f;                     // DIST_THRESH^2
constexpr float INV_EPS = (float)(1.0 / 0.01000001); // 1/(EPSILON + 1e-8)

typedef __attribute__((ext_vector_type(8)))  short bf16x8;
typedef __attribute__((ext_vector_type(16))) float f32x16;

__device__ __forceinline__ int cell_of(float x, float y) {
  int cx = (int)(x * 5.0f); cx = cx < 0 ? 0 : (cx > 4 ? 4 : cx);
  int cy = (int)(y * 5.0f); cy = cy < 0 ? 0 : (cy > 4 ? 4 : cy);
  return cy * 5 + cx;
}

// async 16B/lane global->LDS DMA: LDS dest = wave-uniform base + lane*16.
__device__ __forceinline__ void dma16(const void* g, void* l) {
  __builtin_amdgcn_global_load_lds(
      (const __attribute__((address_space(1))) void*)g,
      (__attribute__((address_space(3))) void*)l, 16, 0, 0);
}

// ------------------------------------------------- fused binning (8 blk) ----
// Per-(side,batch) block: count, scan 25 cells, scatter perm + sorted packs.
// Block 0 zeroes the Zc leak counters.
__global__ __launch_bounds__(256) void k_bin(
    const float* __restrict__ tlocs, const float* __restrict__ slocs,
    const int* __restrict__ tmask, const int* __restrict__ smask,
    int* __restrict__ Zc,
    int* __restrict__ starts_t, int* __restrict__ starts_s,
    int* __restrict__ perm_t, int* __restrict__ perm_s,
    float4* __restrict__ t_sorted, float4* __restrict__ s_sorted) {
  const int which = blockIdx.x & 1, b = blockIdx.x >> 1;   // grid = 2*B
  const float* locs = which ? slocs : tlocs;
  const int*   mask = which ? smask : tmask;
  int* starts       = which ? starts_s : starts_t;
  int* perm         = which ? perm_s : perm_t;
  float4* pack      = which ? s_sorted : t_sorted;
  const int tid = threadIdx.x;
  if (blockIdx.x == 0) Zc[tid] = 0;                        // 256 ints = 1 KB
  __shared__ int cnt[25];
  __shared__ int st[26];
  __shared__ int cur[25];
  if (tid < 25) cnt[tid] = 0;
  __syncthreads();
  for (int i = tid; i < BN; i += 256)
    atomicAdd(&cnt[cell_of(locs[(b * BN + i) * 2], locs[(b * BN + i) * 2 + 1])], 1);
  __syncthreads();
  if (tid == 0) {
    int acc = 0;
    for (int c = 0; c < 25; c++) { st[c] = acc; acc += cnt[c]; }
    st[25] = acc;                                          // == 4096
  }
  __syncthreads();
  if (tid < 25) cur[tid] = st[tid];
  if (tid < 26) starts[b * 32 + tid] = st[tid];
  __syncthreads();
  for (int i = tid; i < BN; i += 256) {
    float x = locs[(b * BN + i) * 2], y = locs[(b * BN + i) * 2 + 1];
    int pos = atomicAdd(&cur[cell_of(x, y)], 1);
    perm[b * BN + pos] = i;
    pack[b * BN + pos] = make_float4(x, y, 0.f, mask[b * BN + i] ? 1.f : 0.f);
  }
}

// -------------------------------------------- feats pre-pack (1024 blk) -----
// fB[b][blk][ch][sl'] u32 = (bf16hi<<16 | bf16lo) of feats[b][perm_s[blk*16+sl]][ch]
// with sl' = sl ^ (((ch>>1)&3)<<2)  (bank swizzle for the k_out A-fragment
// ds_read_b128s: reduces 8-way conflict to 4-way while keeping every 4-u32
// group contiguous and 16B-aligned). One tile = 256x16 u32 = 16 KB, DMA-ready.
__global__ __launch_bounds__(256) void k_pack(
    const float* __restrict__ feats, const int* __restrict__ perm_s,
    unsigned* __restrict__ fB) {
  const int b   = blockIdx.x >> 8;
  const int blk = blockIdx.x & 255;
  const int tid = threadIdx.x;
  __shared__ float fs[16][260];
  __shared__ int   sidx[16];
  if (tid < 16) sidx[tid] = perm_s[b * BN + blk * 16 + tid];
  __syncthreads();
  #pragma unroll
  for (int q = 0; q < 4; q++) {                    // coalesced row reads
    int idx = q * 256 + tid;                       // row = idx>>6, col4 = idx&63
    int r = idx >> 6, c4 = idx & 63;
    float4 v = ((const float4*)feats)[(((b << 12) + sidx[r]) << 6) + c4];
    fs[r][c4 * 4 + 0] = v.x; fs[r][c4 * 4 + 1] = v.y;
    fs[r][c4 * 4 + 2] = v.z; fs[r][c4 * 4 + 3] = v.w;
  }
  __syncthreads();
  const int ch = tid;
  unsigned* dst = fB + ((((size_t)b << 8) + blk) << 12) + ch * 16;
  unsigned pk[16];
  #pragma unroll
  for (int sl = 0; sl < 16; sl++) {
    float f = fs[sl][ch];
    unsigned fb = __float_as_uint(f);
    unsigned hb = fb & 0xFFFF0000u;
    float lo = f - __uint_as_float(hb);
    pk[sl ^ (((ch >> 1) & 3) << 2)] = hb | (__float_as_uint(lo) >> 16);
  }
  #pragma unroll
  for (int q = 0; q < 4; q++)
    ((uint4*)dst)[q] = make_uint4(pk[q*4], pk[q*4+1], pk[q*4+2], pk[q*4+3]);
}

// ------------------------------------------------------ sparse Sinkhorn -----
// r4-verified; see prior rounds' comment for the plain-sum / Z-leak argument.
__global__ __launch_bounds__(256) void k_sink(const float4* __restrict__ opp,
                                              float4* __restrict__ own,
                                              const int* __restrict__ opp_starts,
                                              const int* __restrict__ Zin,
                                              int* __restrict__ Zout,
                                              int zero_invalid) {
  const int wv   = threadIdx.x >> 6;
  const int lane = threadIdx.x & 63;
  const int rowb = blockIdx.x * 16 + wv * 4;
  const int b    = rowb >> 12;
  float4 me[4];
  float  s[4] = {0.f, 0.f, 0.f, 0.f};
  int ryLo = 5, ryHi = -1, rxLo = 5, rxHi = -1;
  #pragma unroll
  for (int i = 0; i < 4; i++) {
    me[i] = own[rowb + i];
    if (me[i].w != 0.f) {
      int cell = cell_of(me[i].x, me[i].y);
      int cy = cell / 5, cx = cell % 5;
      ryLo = min(ryLo, max(cy - 1, 0)); ryHi = max(ryHi, min(cy + 1, 4));
      rxLo = min(rxLo, max(cx - 1, 0)); rxHi = max(rxHi, min(cx + 1, 4));
    }
  }
  for (int ry = ryLo; ry <= ryHi; ry++) {
    const int r0 = opp_starts[b * 32 + ry * 5 + rxLo];
    const int r1 = opp_starts[b * 32 + ry * 5 + rxHi + 1];
    for (int j = r0 + lane; j < r1; j += 64) {
      float4 o = opp[b * BN + j];
      #pragma unroll
      for (int i = 0; i < 4; i++) {
        float dx = me[i].x - o.x, dy = me[i].y - o.y;
        float d2 = fmaf(dx, dx, dy * dy);
        bool  c  = (d2 < T2) && (o.w != 0.f) && (me[i].w != 0.f);
        float t  = c ? fmaf(d2, -INV_EPS, o.z) : -3e30f;
        s[i] += __expf(t);
      }
    }
  }
  #pragma unroll
  for (int i = 0; i < 4; i++)
    for (int off = 32; off > 0; off >>= 1) s[i] += __shfl_xor(s[i], off);
  if (lane == 0) {
    const float Zf = (float)Zin[b];
    #pragma unroll
    for (int i = 0; i < 4; i++) {
      float ss  = s[i] + Zf;
      float val = (ss > 0.f) ? -logf(ss) : 1.0e9f;
      if (zero_invalid && me[i].w == 0.f) val = 0.f;
      own[rowb + i] = make_float4(me[i].x, me[i].y, val, me[i].w);
      if (val == 1.0e9f) atomicAdd(&Zout[b], 1);
    }
  }
}

// ------------------------------------------------- sparse attn @ feats ------
// MFMA v2 on the r6 chassis. Tile 32tm x 256ch; K = 16 src per round, aligned
// to fB 16-blocks (over-scan cols outside [s0,s1) masked to attn==0).
//   DMA: 16KB pre-packed fB tile -> LDS, double-buffered, r6 single-barrier.
//   B (attn) built straight in registers: lane = (tm=lane&31, k8=lane>>5),
//   EXACTLY mfma_f32_32x32x16_bf16's B layout -> no attn LDS at all.
//   A (feats^T) via 2 ds_read_b128/frag from the swizzled tile.
//   3 bf16 terms AhBh+AhBl+AlBh (drops AlBl ~2^-16 rel; r1/r2 harness-passed).
//   D: col=lane&31(tm), row=(reg&3)+8(reg>>2)+4(lane>>5) (m74/m101-verified);
//   bounced via LDS (stride 268) into the byte-identical r6 atomic flush.
#define MAXCH 12   // 12*32 = 384 targets/cell upper bound

__global__ __launch_bounds__(256) void k_out(
    const unsigned* __restrict__ fB, const float4* __restrict__ t_sorted,
    const float4* __restrict__ s_sorted, const int* __restrict__ perm_t,
    const int* __restrict__ starts_t, const int* __restrict__ starts_s,
    float* __restrict__ out) {
  const int b = blockIdx.z;
  const int cell = blockIdx.y / 3, rsel = blockIdx.y % 3;
  const int cy = cell / 5, cx = cell % 5;
  const int ry = cy + rsel - 1;
  if (ry < 0 || ry > 4) return;                            // uniform early-exit
  const int t0 = starts_t[b * 32 + cell], t1 = starts_t[b * 32 + cell + 1];
  const int base = t0 + blockIdx.x * 32;
  if (base >= t1) return;
  const int rx0 = max(cx - 1, 0), rx1 = min(cx + 1, 4);
  const int s0 = starts_s[b * 32 + ry * 5 + rx0];
  const int s1 = starts_s[b * 32 + ry * 5 + rx1 + 1];
  if (s0 >= s1) return;
  const int nt = min(32, t1 - base);

  __shared__ __align__(16) unsigned pool[8576];  // 2x16KB tiles | 34.3KB Dl bounce
  __shared__ float4 tL[32];
  __shared__ int    morg[32];

  const int tid  = threadIdx.x;
  const int lane = tid & 63;
  const int w    = tid >> 6;

  if (tid < 32) {
    if (tid < nt) {
      tL[tid]   = t_sorted[b * BN + base + tid];
      morg[tid] = perm_t[b * BN + base + tid];
    } else {
      tL[tid]   = make_float4(0.f, 0.f, 0.f, 0.f);         // tv=0 -> attn 0
      morg[tid] = 0;
    }
  }
  __syncthreads();

  const int kg = lane >> 5;                  // k-half: src kg*8 .. +7
  const int ln = lane & 31;                  // n(tm) for B/D, m(ch) for A
  const float4 t4a = tL[ln];                 // this lane's attn target row
  const int sB = b * BN;

  const int blk0 = s0 >> 4;
  const int nBlk = ((s1 + 15) >> 4) - blk0;

  // ---- prologue: DMA tile(0) into buf0 + s-row prefetch for round 0 --------
  {
    const unsigned* g = fB + ((((size_t)b << 8) + blk0) << 12);
    #pragma unroll
    for (int q = 0; q < 4; q++)
      dma16(g + (w * 4 + q) * 256 + lane * 4,
            (void*)(pool + (w * 4 + q) * 256));
  }
  float4 ps[8], pn[8];
  {
    int j0 = blk0 * 16 + kg * 8;
    #pragma unroll
    for (int e = 0; e < 8; e++)
      ps[e] = s_sorted[sB + min(j0 + e, BN - 1)];
  }

  f32x16 acc0, acc1;
  #pragma unroll
  for (int i = 0; i < 16; i++) { acc0[i] = 0.f; acc1[i] = 0.f; }

  int buf = 0;
  for (int r = 0; r < nBlk; r++, buf ^= 1) {
    asm volatile("s_waitcnt vmcnt(0)" ::: "memory");       // DMA + prefetch done
    __builtin_amdgcn_s_barrier();                          // publish to all waves
    __builtin_amdgcn_sched_barrier(0);
    const bool more = (r + 1 < nBlk);                      // uniform
    if (more) {                                            // issue next round
      const unsigned* g = fB + ((((size_t)b << 8) + blk0 + r + 1) << 12);
      #pragma unroll
      for (int q = 0; q < 4; q++)
        dma16(g + (w * 4 + q) * 256 + lane * 4,
              (void*)(pool + (buf ^ 1) * 4096 + (w * 4 + q) * 256));
      int j0n = (blk0 + r + 1) * 16 + kg * 8;
      #pragma unroll
      for (int e = 0; e < 8; e++)
        pn[e] = s_sorted[sB + min(j0n + e, BN - 1)];
    }
    // ---- B fragments (attn) straight into registers ------------------------
    const int j0 = (blk0 + r) * 16 + kg * 8;
    unsigned ahv[8], alv[8];
    #pragma unroll
    for (int e = 0; e < 8; e++) {
      float4 s4 = ps[e];
      int j = j0 + e;
      float dx = t4a.x - s4.x, dy = t4a.y - s4.y;
      float d2 = fmaf(dx, dx, dy * dy);
      bool  c  = (j >= s0) && (j < s1) && (d2 < T2) &&
                 (s4.w != 0.f) && (t4a.w != 0.f);
      float a  = c ? __expf(fmaf(d2, -INV_EPS, t4a.z + s4.z)) : 0.f;
      unsigned ab = __float_as_uint(a);
      unsigned hb = ab & 0xFFFF0000u;
      float alo = a - __uint_as_float(hb);
      ahv[e] = ab >> 16;
      alv[e] = __float_as_uint(alo) >> 16;
    }
    union { unsigned u[4]; bf16x8 v; } BH, BL;
    #pragma unroll
    for (int i = 0; i < 4; i++) {
      BH.u[i] = ahv[2*i] | (ahv[2*i+1] << 16);
      BL.u[i] = alv[2*i] | (alv[2*i+1] << 16);
    }
    // ---- A fragments + 6 MFMA ----------------------------------------------
    const unsigned* tile = pool + buf * 4096;
    #pragma unroll
    for (int mt = 0; mt < 2; mt++) {
      const int chl = w * 64 + mt * 32 + ln;
      const int xv  = (chl >> 1) & 3;
      const int g0  = ((kg << 1) | 0) ^ xv;
      const int g1  = ((kg << 1) | 1) ^ xv;
      union { uint4 q[2]; unsigned u[8]; } A;
      A.q[0] = *(const uint4*)(tile + chl * 16 + g0 * 4);
      A.q[1] = *(const uint4*)(tile + chl * 16 + g1 * 4);
      union { unsigned u[4]; bf16x8 v; } AH, AL;
      #pragma unroll
      for (int i = 0; i < 4; i++) {
        AH.u[i] = (A.u[2*i] >> 16)     | (A.u[2*i+1] & 0xFFFF0000u);
        AL.u[i] = (A.u[2*i] & 0xFFFFu) | (A.u[2*i+1] << 16);
      }
      if (mt == 0) {
        acc0 = __builtin_amdgcn_mfma_f32_32x32x16_bf16(AH.v, BH.v, acc0, 0, 0, 0);
        acc0 = __builtin_amdgcn_mfma_f32_32x32x16_bf16(AH.v, BL.v, acc0, 0, 0, 0);
        acc0 = __builtin_amdgcn_mfma_f32_32x32x16_bf16(AL.v, BH.v, acc0, 0, 0, 0);
      } else {
        acc1 = __builtin_amdgcn_mfma_f32_32x32x16_bf16(AH.v, BH.v, acc1, 0, 0, 0);
        acc1 = __builtin_amdgcn_mfma_f32_32x32x16_bf16(AH.v, BL.v, acc1, 0, 0, 0);
        acc1 = __builtin_amdgcn_mfma_f32_32x32x16_bf16(AL.v, BH.v, acc1, 0, 0, 0);
      }
    }
    #pragma unroll
    for (int e = 0; e < 8; e++) ps[e] = pn[e];             // rotate prefetch
  }

  // ---- epilogue: D -> Dl[tm][ch] (stride 268) -> r6 atomic flush -----------
  __syncthreads();                           // all MAC reads of pool done
  float* Dl = (float*)pool;
  #pragma unroll
  for (int mt = 0; mt < 2; mt++) {
    #pragma unroll
    for (int rg = 0; rg < 4; rg++) {         // regs rg*4..+3 -> rows 8rg+4kg..+3
      int chb = w * 64 + mt * 32 + 8 * rg + 4 * kg;
      float4 v;
      if (mt == 0) v = make_float4(acc0[rg*4], acc0[rg*4+1], acc0[rg*4+2], acc0[rg*4+3]);
      else         v = make_float4(acc1[rg*4], acc1[rg*4+1], acc1[rg*4+2], acc1[rg*4+3]);
      *(float4*)&Dl[ln * 268 + chb] = v;
    }
  }
  __syncthreads();
  {
    const int tmg = tid >> 5, chg = tid & 31;
    #pragma unroll
    for (int i = 0; i < 4; i++) {
      int tm = tmg * 4 + i;
      if (tm < nt) {
        float* op = out + (((b << 12) + morg[tm]) << 8) + chg * 4;
        float4 d0 = *(float4*)&Dl[tm * 268 + chg * 4];
        float4 d1 = *(float4*)&Dl[tm * 268 + 128 + chg * 4];
        atomicAdd(op + 0, d0.x); atomicAdd(op + 1, d0.y);
        atomicAdd(op + 2, d0.z); atomicAdd(op + 3, d0.w);
        atomicAdd(op + 128, d1.x); atomicAdd(op + 129, d1.y);
        atomicAdd(op + 130, d1.z); atomicAdd(op + 131, d1.w);
      }
    }
  }
}

// ----------------------------------------------------------------- launch ---
extern "C" void kernel_launch(void* const* d_in, const int* in_sizes, int n_in,
                              void* d_out, int out_size, void* d_ws, size_t ws_size,
                              hipStream_t stream) {
  const float* feats = (const float*)d_in[0];   // [B,N,C] f32
  const float* slocs = (const float*)d_in[1];   // [B,N,2] f32
  const float* tlocs = (const float*)d_in[2];   // [B,M,2] f32
  const int*   smask = (const int*)d_in[3];     // [B,N] int32 (bool)
  const int*   tmask = (const int*)d_in[4];     // [B,M] int32 (bool)
  float* out = (float*)d_out;

  char* ws = (char*)d_ws;                       // ~660 KB + 16 MB fB
  int*    Zc       = (int*)(ws + 1024);         //   256 ints; slot 0 stays 0
  int*    starts_t = (int*)(ws + 2048);         //   512 B
  int*    starts_s = (int*)(ws + 2560);         //   512 B
  int*    perm_t   = (int*)(ws + 4096);         //   64 KB
  int*    perm_s   = (int*)(ws + 69632);        //   64 KB
  float4* s_sorted = (float4*)(ws + 135168);    //  256 KB (x,y,v,sv) cell-sorted
  float4* t_sorted = (float4*)(ws + 397312);    //  256 KB (x,y,u,tv) cell-sorted
  unsigned* fB     = (unsigned*)(ws + 663552);  // 16 MB packed feats tiles

  hipMemsetAsync(out, 0, (size_t)out_size * sizeof(float), stream);
  k_bin<<<8, 256, 0, stream>>>(tlocs, slocs, tmask, smask, Zc,
                               starts_t, starts_s, perm_t, perm_s,
                               t_sorted, s_sorted);
  k_pack<<<1024, 256, 0, stream>>>(feats, perm_s, fB);
  for (int it = 0; it < 3; it++) {
    k_sink<<<1024, 256, 0, stream>>>(s_sorted, t_sorted, starts_s,
                                     Zc + (it == 0 ? 0 : (2 * it) * 4),
                                     Zc + (2 * it + 1) * 4, 0);
    k_sink<<<1024, 256, 0, stream>>>(t_sorted, s_sorted, starts_t,
                                     Zc + (2 * it + 1) * 4,
                                     Zc + (2 * it + 2) * 4, 1);
  }
  k_out<<<dim3(MAXCH, 75, BB), 256, 0, stream>>>(fB, t_sorted, s_sorted,
                                                 perm_t, starts_t, starts_s,
                                                 out);
}